// Round 6
// baseline (426.632 us; speedup 1.0000x reference)
//
#include <hip/hip_runtime.h>

#define NB 8
#define NC 256          // K
#define IMG 3600
#define TEMPF 0.2f

typedef unsigned short u16;
typedef __bf16 bf16x8 __attribute__((ext_vector_type(8)));
typedef float  f32x4  __attribute__((ext_vector_type(4)));
typedef unsigned short u16x8 __attribute__((ext_vector_type(8)));

__device__ __forceinline__ u16 f2bf(float f) {
  unsigned u = __builtin_bit_cast(unsigned, f);
  u += 0x7FFFu + ((u >> 16) & 1u);          // round-to-nearest-even
  return (u16)(u >> 16);
}

__device__ __forceinline__ void gld16(const void* g, void* l) {
  __builtin_amdgcn_global_load_lds(
      (__attribute__((address_space(1))) void*)g,
      (__attribute__((address_space(3))) void*)l, 16, 0, 0);
}

// ---------------------------------------------------------------------------
// Gather + cast, k-chunk-major layout:
//   des[b][kc][row][j] = p[b][kc*8+j][pix(row)]   (kc = 0..31, j = 0..7)
// MFMA fragment loads hit 4x256-B contiguous segments (lane=row).
// Rows >= M zero-filled.
// ---------------------------------------------------------------------------
__global__ __launch_bounds__(256)
void gather_kernel(const float* __restrict__ p1, const float* __restrict__ p2,
                   const int* __restrict__ y1, const int* __restrict__ x1,
                   const int* __restrict__ y2, const int* __restrict__ x2,
                   u16* __restrict__ des1, u16* __restrict__ des2,
                   int M, int Mp) {
  const int which = blockIdx.z >> 3;       // 0 -> des1, 1 -> des2
  const int b = blockIdx.z & 7;
  const float* P = (which ? p2 : p1) + (size_t)b * NC * IMG;
  const int* Y = which ? y2 : y1;
  const int* X = which ? x2 : x1;
  u16* D = (which ? des2 : des1) + (size_t)b * Mp * NC;

  const int t = threadIdx.x;
  const int row_l = t & 63;                // lane = row -> coalesced store
  const int kc = blockIdx.y * 4 + (t >> 6);
  const int m = blockIdx.x * 64 + row_l;
  const bool mv = m < M;
  const int pix = mv ? (Y[m] * 60 + X[m]) : 0;
  const float* src = P + (size_t)(kc * 8) * IMG + pix;

  u16x8 h;
#pragma unroll
  for (int j = 0; j < 8; ++j) {
    float v = mv ? src[(size_t)j * IMG] : 0.f;
    h[j] = f2bf(v);
  }
  *(u16x8*)(D + ((size_t)kc * Mp + m) * 8) = h;
}

// ---------------------------------------------------------------------------
// MFMA GEMM + fused exp / row / col / diag.
// Block = 64 A-rows x full n-range, batch = blockIdx&7 (XCD pin -> B stays
// in that XCD's L2). A staged once to LDS (32 KB); after one barrier the
// 4 waves run fully independent, each sweeping 28 disjoint strip-PAIRS
// (pair p = w + 4*j, 32 cols each). Per pair: 16 B-frag global loads
// (double-buffered one pair ahead), 32 ds_read_b128 A-frag reads
// (pipelined one ks ahead), 64 MFMAs, 32 exps. Pair order staggered by
// mt%28 so same-batch blocks never collide on col_sum atomics.
// Frag layouts (16x16x32 bf16): A/B[row=l15][k=quad*8+j]; C/D col=l15,
// row=quad*4+reg.
// ---------------------------------------------------------------------------
__global__ __launch_bounds__(256, 2)
void mfma_lse(const u16* __restrict__ des1, const u16* __restrict__ des2,
              float* __restrict__ row_sum, float* __restrict__ col_sum,
              float* __restrict__ diag, int M, int Mp) {
  __shared__ __align__(16) u16 Asl[32 * 64 * 8];   // [kc][row], 16B chunks, 32 KB

  const int b  = blockIdx.x & 7;
  const int mt = blockIdx.x >> 3;
  const int m0 = mt * 64;
  const int t = threadIdx.x;
  const int w = t >> 6, lane = t & 63;
  const int quad = lane >> 4, l15 = lane & 15;

  // ---- stage A (64 rows x 32 k-chunks) into LDS, wave-contiguous ----
  const u16* D1 = des1 + (size_t)b * Mp * NC;
#pragma unroll
  for (int it = 0; it < 8; ++it) {
    int idx = it * 256 + t;                 // kc = idx>>6, row = idx&63
    gld16(D1 + ((size_t)(idx >> 6) * Mp + m0 + (idx & 63)) * 8, Asl + idx * 8);
  }

  const u16* D2 = des2 + (size_t)b * Mp * NC;
  auto loadBpair = [&](bf16x8 (&dst)[2][8], int p) {
#pragma unroll
    for (int j = 0; j < 2; ++j)
#pragma unroll
      for (int ks = 0; ks < 8; ++ks)
        dst[j][ks] = *(const bf16x8*)(
            D2 + ((size_t)(ks * 4 + quad) * Mp + (p * 2 + j) * 16 + l15) * 8);
  };

  float rowReg[16];
#pragma unroll
  for (int i = 0; i < 16; ++i) rowReg[i] = 0.f;

  auto do_pair = [&](const bf16x8 (&B)[2][8], int p) {
    f32x4 acc[4][2] = {};
    bf16x8 af[2][4];
#pragma unroll
    for (int i = 0; i < 4; ++i)
      af[0][i] = *(const bf16x8*)&Asl[((quad)*64 + i * 16 + l15) * 8];
#pragma unroll
    for (int ks = 0; ks < 8; ++ks) {
      if (ks + 1 < 8) {
#pragma unroll
        for (int i = 0; i < 4; ++i)
          af[(ks + 1) & 1][i] = *(const bf16x8*)&Asl[
              (((ks + 1) * 4 + quad) * 64 + i * 16 + l15) * 8];
      }
#pragma unroll
      for (int i = 0; i < 4; ++i) {
        acc[i][0] = __builtin_amdgcn_mfma_f32_16x16x32_bf16(
            af[ks & 1][i], B[0][ks], acc[i][0], 0, 0, 0);
        acc[i][1] = __builtin_amdgcn_mfma_f32_16x16x32_bf16(
            af[ks & 1][i], B[1][ks], acc[i][1], 0, 0, 0);
      }
    }

    // ---- epilogue: exp + row/col partials ----
    float cp[2] = {0.f, 0.f};
#pragma unroll
    for (int j = 0; j < 2; ++j) {
      const int colg = (p * 2 + j) * 16 + l15;
      const bool nv = colg < M;
#pragma unroll
      for (int i = 0; i < 4; ++i)
#pragma unroll
        for (int r = 0; r < 4; ++r) {
          const int rowg = m0 + i * 16 + quad * 4 + r;
          float e = (nv && rowg < M) ? __expf(TEMPF * acc[i][j][r]) : 0.f;
          rowReg[i * 4 + r] += e;
          cp[j] += e;
        }
    }
#pragma unroll
    for (int j = 0; j < 2; ++j) {
      float c = cp[j];
      c += __shfl_xor(c, 16); c += __shfl_xor(c, 32);
      int colg = (p * 2 + j) * 16 + l15;
      if (quad == 0 && colg < M) atomicAdd(&col_sum[b * M + colg], c);
    }
    // diag: pair p covers cols m0+pd*32..+31 when pd = p - 2*mt is 0 or 1
    const int pd = p - 2 * mt;
    if (pd == 0 || pd == 1) {
#pragma unroll
      for (int j = 0; j < 2; ++j) {
        const int i = pd * 2 + j;
#pragma unroll
        for (int r = 0; r < 4; ++r) {
          int rowg = m0 + i * 16 + quad * 4 + r;
          if (l15 == quad * 4 + r && rowg < M)
            diag[b * M + rowg] = TEMPF * acc[i][j][r];
        }
      }
    }
  };

  // ---- main sweep: 28 pairs/wave, staggered start, B ping-pong ----
  const int j0 = mt % 28;
  auto pidx = [&](int jj) { int j = jj + j0; if (j >= 28) j -= 28; return w + 4 * j; };

  bf16x8 bcur[2][8], bnxt[2][8];
  loadBpair(bcur, pidx(0));
  __syncthreads();                           // A staged (drains B0 too)

  for (int jj = 0; jj < 28; jj += 2) {
    loadBpair(bnxt, pidx(jj + 1));
    do_pair(bcur, pidx(jj));
    if (jj + 2 < 28) loadBpair(bcur, pidx(jj + 2));
    do_pair(bnxt, pidx(jj + 1));
  }

  // ---- row sums: reduce over this wave's 16 cols (l15), then atomic ----
#pragma unroll
  for (int i = 0; i < 4; ++i)
#pragma unroll
    for (int r = 0; r < 4; ++r) {
      float v = rowReg[i * 4 + r];
      v += __shfl_xor(v, 1); v += __shfl_xor(v, 2);
      v += __shfl_xor(v, 4); v += __shfl_xor(v, 8);
      int rowg = m0 + i * 16 + quad * 4 + r;
      if (l15 == 0 && rowg < M) atomicAdd(&row_sum[b * M + rowg], v);
    }
}

// ---------------------------------------------------------------------------
// loss partial: mean( log(row_sum) + log(col_sum) - 2*dist_diag )
// ---------------------------------------------------------------------------
__global__ __launch_bounds__(256)
void finalize(const float* __restrict__ row_sum, const float* __restrict__ col_sum,
              const float* __restrict__ diag, float* __restrict__ out,
              int total, float inv_total) {
  __shared__ float red[4];
  int i = blockIdx.x * 256 + threadIdx.x;
  float s = 0.f;
  if (i < total)
    s = logf(row_sum[i]) + logf(col_sum[i]) - 2.f * diag[i];
#pragma unroll
  for (int o = 1; o < 64; o <<= 1) s += __shfl_xor(s, o);
  const int lane = threadIdx.x & 63, wid = threadIdx.x >> 6;
  if (lane == 0) red[wid] = s;
  __syncthreads();
  if (threadIdx.x == 0)
    atomicAdd(out, (red[0] + red[1] + red[2] + red[3]) * inv_total);
}

extern "C" void kernel_launch(void* const* d_in, const int* in_sizes, int n_in,
                              void* d_out, int out_size, void* d_ws, size_t ws_size,
                              hipStream_t stream) {
  const float* p1 = (const float*)d_in[0];
  const float* p2 = (const float*)d_in[1];
  const int* y1 = (const int*)d_in[2];
  const int* x1 = (const int*)d_in[3];
  const int* y2 = (const int*)d_in[4];
  const int* x2 = (const int*)d_in[5];
  const int M = in_sizes[2];                    // 3540
  const int Mp = ((M + 63) / 64) * 64;          // 3584

  float* row_sum = (float*)d_ws;                // NB*M
  float* col_sum = row_sum + (size_t)NB * M;    // NB*M
  float* diagbuf = col_sum + (size_t)NB * M;    // NB*M
  size_t off = (((size_t)3 * NB * M * sizeof(float)) + 255) & ~(size_t)255;
  u16* des1 = (u16*)((char*)d_ws + off);        // NB*Mp*NC bf16, k-chunk-major
  u16* des2 = des1 + (size_t)NB * Mp * NC;

  hipMemsetAsync(d_ws, 0, (size_t)2 * NB * M * sizeof(float), stream);
  hipMemsetAsync(d_out, 0, sizeof(float), stream);

  dim3 ggrid(Mp / 64, NC / 32, 2 * NB);         // (56, 8, 16)
  gather_kernel<<<ggrid, 256, 0, stream>>>(p1, p2, y1, x1, y2, x2, des1, des2, M, Mp);

  mfma_lse<<<dim3(NB * Mp / 64), 256, 0, stream>>>(des1, des2, row_sum, col_sum,
                                                   diagbuf, M, Mp);

  int total = NB * M;
  finalize<<<(total + 255) / 256, 256, 0, stream>>>(row_sum, col_sum, diagbuf,
                                                    (float*)d_out, total,
                                                    1.f / (float)total);
}

// Round 7
// 217.881 us; speedup vs baseline: 1.9581x; 1.9581x over previous
//
#include <hip/hip_runtime.h>

#define NB 8
#define NC 256          // K
#define IMG 3600
#define TEMPF 0.2f
#define MP 3584         // M padded to multiple of 128
#define NRB 28          // MP/128 row/col tiles
#define NKB 4           // NC/64 K-tiles

typedef unsigned short u16;
typedef __bf16 bf16x8 __attribute__((ext_vector_type(8)));
typedef float  f32x4  __attribute__((ext_vector_type(4)));
typedef unsigned short u16x8 __attribute__((ext_vector_type(8)));

__device__ __forceinline__ u16 f2bf(float f) {
  unsigned u = __builtin_bit_cast(unsigned, f);
  u += 0x7FFFu + ((u >> 16) & 1u);          // round-to-nearest-even
  return (u16)(u >> 16);
}

__device__ __forceinline__ void gld16(const void* g, void* l) {
  __builtin_amdgcn_global_load_lds(
      (__attribute__((address_space(1))) void*)g,
      (__attribute__((address_space(3))) void*)l, 16, 0, 0);
}

// ---------------------------------------------------------------------------
// Gather + cast into TILED, BANK-SWIZZLED bf16 layout:
//   chunk(b, kb, rb, row128, slot) holds k-chunk ch = slot ^ (row & 7)
//   of global row m = rb*128+row128, k = kb*64 + ch*8 + 0..7.
//   chunk index = (((b*NKB+kb)*NRB + rb)*128 + row128)*8 + slot  (x8 u16)
// -> GEMM staging of one 128x64 tile is one contiguous 16 KB block
//    (global_load_lds-compatible), and swizzled slots make every aligned
//    8-lane group of a ds_read_b128 frag read hit 8 distinct bank groups.
// Rows >= M zero-filled.
// ---------------------------------------------------------------------------
__global__ __launch_bounds__(256)
void gather_kernel(const float* __restrict__ p1, const float* __restrict__ p2,
                   const int* __restrict__ y1, const int* __restrict__ x1,
                   const int* __restrict__ y2, const int* __restrict__ x2,
                   u16* __restrict__ des1, u16* __restrict__ des2, int M) {
  const int which = blockIdx.z >> 3;       // 0 -> des1, 1 -> des2
  const int b = blockIdx.z & 7;
  const float* P = (which ? p2 : p1) + (size_t)b * NC * IMG;
  const int* Y = which ? y2 : y1;
  const int* X = which ? x2 : x1;
  u16* D = which ? des2 : des1;

  const int t = threadIdx.x;
  const int row64 = t & 63;                // lane = row -> coalesced loads
  const int kc = blockIdx.y * 4 + (t >> 6); // global 16B k-chunk, 0..31
  const int m = blockIdx.x * 64 + row64;
  const bool mv = m < M;
  const int pix = mv ? (Y[m] * 60 + X[m]) : 0;
  const float* src = P + (size_t)(kc * 8) * IMG + pix;

  u16x8 h;
#pragma unroll
  for (int j = 0; j < 8; ++j) {
    float v = mv ? src[(size_t)j * IMG] : 0.f;
    h[j] = f2bf(v);
  }
  const int kb = kc >> 3, ch = kc & 7;
  const int rb = m >> 7, row128 = m & 127;
  const int slot = ch ^ (m & 7);
  size_t chunk = ((((size_t)b * NKB + kb) * NRB + rb) * 128 + row128) * 8 + slot;
  *(u16x8*)(D + chunk * 8) = h;
}

// ---------------------------------------------------------------------------
// MFMA GEMM + fused exp / row / col / diag.   128x128 C-tile per block.
// LDS: double-buffered (A-tile 16 KB + B-tile 16 KB) x 2 = 64 KB
//   -> 2 blocks/CU (8 waves, 2/SIMD) so barrier stalls overlap across blocks.
// K-loop: 4 iters of BK=64; stage kb+1 (8 gld16/thread), s_waitcnt vmcnt(8)
// (waits kb only -> kb+1 stays in flight), raw s_barrier. Never vmcnt(0)
// until the last iter. Frag reads: ds_read_b128 at swizzled slots
// (conflict-free). 4 waves in 2x2, wave tile 64x64 = 4x4 MFMAs per k-slice.
// Frag layouts (16x16x32 bf16): A/B[row=l15][k=quad*8+j]; C/D col=l15,
// row=quad*4+reg.   batch = blockIdx&7 -> XCD-pinned L2 working set.
// ---------------------------------------------------------------------------
__global__ __launch_bounds__(256, 2)
void mfma_lse(const u16* __restrict__ des1, const u16* __restrict__ des2,
              float* __restrict__ row_sum, float* __restrict__ col_sum,
              float* __restrict__ diag, int M) {
  __shared__ __align__(16) u16 bufA[2][8192];   // 16 KB each
  __shared__ __align__(16) u16 bufB[2][8192];

  const int flat = blockIdx.x;
  const int b = flat & 7;
  const int f = flat >> 3;
  const int mt = f % NRB;
  const int nt = (f / NRB + mt) % NRB;          // stagger col-atomic order
  const int m0 = mt * 128, n0 = nt * 128;
  const int t = threadIdx.x;
  const int w = t >> 6, lane = t & 63;
  const int wm = w >> 1, wn = w & 1;
  const int quad = lane >> 4, l15 = lane & 15;

  auto stage = [&](int kb, int sel) {
    const u16* Ak = des1 + (((size_t)b * NKB + kb) * NRB + mt) * 8192;
    const u16* Bk = des2 + (((size_t)b * NKB + kb) * NRB + nt) * 8192;
#pragma unroll
    for (int i = 0; i < 4; ++i) {
      int idx = i * 256 + t;
      gld16(Ak + (size_t)idx * 8, &bufA[sel][idx * 8]);
      gld16(Bk + (size_t)idx * 8, &bufB[sel][idx * 8]);
    }
  };

  f32x4 acc[4][4] = {};

  stage(0, 0);
  for (int kb = 0; kb < NKB; ++kb) {
    if (kb + 1 < NKB) {
      stage(kb + 1, (kb + 1) & 1);
      asm volatile("s_waitcnt vmcnt(8)" ::: "memory");   // kb's tile resident
    } else {
      asm volatile("s_waitcnt vmcnt(0)" ::: "memory");
    }
    asm volatile("s_barrier" ::: "memory");

    const u16* As = bufA[kb & 1];
    const u16* Bs = bufB[kb & 1];
#pragma unroll
    for (int ks = 0; ks < 2; ++ks) {
      bf16x8 af[4], bf[4];
#pragma unroll
      for (int i = 0; i < 4; ++i) {
        int row = wm * 64 + i * 16 + l15;
        int slot = (ks * 4 + quad) ^ (row & 7);
        af[i] = *(const bf16x8*)&As[row * 64 + slot * 8];
      }
#pragma unroll
      for (int j = 0; j < 4; ++j) {
        int row = wn * 64 + j * 16 + l15;
        int slot = (ks * 4 + quad) ^ (row & 7);
        bf[j] = *(const bf16x8*)&Bs[row * 64 + slot * 8];
      }
#pragma unroll
      for (int i = 0; i < 4; ++i)
#pragma unroll
        for (int j = 0; j < 4; ++j)
          acc[i][j] = __builtin_amdgcn_mfma_f32_16x16x32_bf16(
              af[i], bf[j], acc[i][j], 0, 0, 0);
    }
    asm volatile("s_waitcnt lgkmcnt(0)" ::: "memory");   // frag reads done
    asm volatile("s_barrier" ::: "memory");              // before overwrite
  }

  // ---- epilogue: exp + row/col reductions + diag (no LDS, no barriers) ----
  float cp[4] = {0.f, 0.f, 0.f, 0.f};
#pragma unroll
  for (int i = 0; i < 4; ++i)
#pragma unroll
    for (int r = 0; r < 4; ++r) {
      const int rowg = m0 + wm * 64 + i * 16 + quad * 4 + r;
      const bool mv = rowg < M;
      float rv = 0.f;
#pragma unroll
      for (int j = 0; j < 4; ++j) {
        const int colg = n0 + wn * 64 + j * 16 + l15;
        float e = (mv && colg < M) ? __expf(TEMPF * acc[i][j][r]) : 0.f;
        rv += e;
        cp[j] += e;
      }
      rv += __shfl_xor(rv, 1); rv += __shfl_xor(rv, 2);
      rv += __shfl_xor(rv, 4); rv += __shfl_xor(rv, 8);
      if (l15 == 0 && mv) atomicAdd(&row_sum[b * M + rowg], rv);
    }
#pragma unroll
  for (int j = 0; j < 4; ++j) {
    float c = cp[j];
    c += __shfl_xor(c, 16); c += __shfl_xor(c, 32);
    const int colg = n0 + wn * 64 + j * 16 + l15;
    if (quad == 0 && colg < M) atomicAdd(&col_sum[b * M + colg], c);
  }
  if (mt == nt && wm == wn) {
#pragma unroll
    for (int i = 0; i < 4; ++i)
#pragma unroll
      for (int r = 0; r < 4; ++r) {
        const int rowg = m0 + wm * 64 + i * 16 + quad * 4 + r;
        if (l15 == quad * 4 + r && rowg < M)
          diag[b * M + rowg] = TEMPF * acc[i][i][r];
      }
  }
}

// ---------------------------------------------------------------------------
// loss partial: mean( log(row_sum) + log(col_sum) - 2*dist_diag )
// ---------------------------------------------------------------------------
__global__ __launch_bounds__(256)
void finalize(const float* __restrict__ row_sum, const float* __restrict__ col_sum,
              const float* __restrict__ diag, float* __restrict__ out,
              int total, float inv_total) {
  __shared__ float red[4];
  int i = blockIdx.x * 256 + threadIdx.x;
  float s = 0.f;
  if (i < total)
    s = logf(row_sum[i]) + logf(col_sum[i]) - 2.f * diag[i];
#pragma unroll
  for (int o = 1; o < 64; o <<= 1) s += __shfl_xor(s, o);
  const int lane = threadIdx.x & 63, wid = threadIdx.x >> 6;
  if (lane == 0) red[wid] = s;
  __syncthreads();
  if (threadIdx.x == 0)
    atomicAdd(out, (red[0] + red[1] + red[2] + red[3]) * inv_total);
}

extern "C" void kernel_launch(void* const* d_in, const int* in_sizes, int n_in,
                              void* d_out, int out_size, void* d_ws, size_t ws_size,
                              hipStream_t stream) {
  const float* p1 = (const float*)d_in[0];
  const float* p2 = (const float*)d_in[1];
  const int* y1 = (const int*)d_in[2];
  const int* x1 = (const int*)d_in[3];
  const int* y2 = (const int*)d_in[4];
  const int* x2 = (const int*)d_in[5];
  const int M = in_sizes[2];                    // 3540 (<= MP)

  float* row_sum = (float*)d_ws;                // NB*M
  float* col_sum = row_sum + (size_t)NB * M;    // NB*M
  float* diagbuf = col_sum + (size_t)NB * M;    // NB*M
  size_t off = (((size_t)3 * NB * M * sizeof(float)) + 255) & ~(size_t)255;
  u16* des1 = (u16*)((char*)d_ws + off);        // NB*MP*NC bf16, tiled+swizzled
  u16* des2 = des1 + (size_t)NB * MP * NC;

  hipMemsetAsync(d_ws, 0, (size_t)2 * NB * M * sizeof(float), stream);
  hipMemsetAsync(d_out, 0, sizeof(float), stream);

  dim3 ggrid(MP / 64, 8, 2 * NB);               // (56, 8, 16)
  gather_kernel<<<ggrid, 256, 0, stream>>>(p1, p2, y1, x1, y2, x2, des1, des2, M);

  mfma_lse<<<dim3(NB * NRB * NRB), 256, 0, stream>>>(des1, des2, row_sum,
                                                     col_sum, diagbuf, M);

  int total = NB * M;
  finalize<<<(total + 255) / 256, 256, 0, stream>>>(row_sum, col_sum, diagbuf,
                                                    (float*)d_out, total,
                                                    1.f / (float)total);
}